// Round 14
// baseline (726.319 us; speedup 1.0000x reference)
//
#include <hip/hip_runtime.h>
#include <hip/hip_bf16.h>
#include <math.h>

#define V     10000
#define EMB   512
#define H     1024
#define H3    3072
#define SEQ   64
#define NPAD  10048   // padded N for score partials
#define NPH   129     // history slots (phases 0..128)

typedef __attribute__((ext_vector_type(8))) unsigned short us8;
typedef __attribute__((ext_vector_type(8))) unsigned u32x8;
typedef unsigned long long ull;

__device__ __forceinline__ float sigmoidf_(float x) { return 1.0f / (1.0f + expf(-x)); }
__device__ __forceinline__ float bf2f(unsigned short u) { return __uint_as_float(((unsigned)u) << 16); }
__device__ __forceinline__ float lof(unsigned u) { return __uint_as_float(u << 16); }
__device__ __forceinline__ float hif(unsigned u) { return __uint_as_float(u & 0xffff0000u); }
__device__ __forceinline__ unsigned short f2bf_rne(float f) {
    unsigned u = __float_as_uint(f);
    unsigned r = u + 0x7FFF + ((u >> 16) & 1);
    return (unsigned short)(r >> 16);
}
__device__ __forceinline__ ull packh(float v) {
    return (ull)__float_as_uint(v) | (1ULL << 32);
}

// ---------------- merged prep: rec conversion + history init + embedding + out_W conversion ----------------
// grid.x = 9216 (rec conv) + 516 (init) + 128 (embed) + 5000 (out_W conv) = 14860, 256 threads
struct PrepArgs {
    const float* src[6]; unsigned short* dst0; int doConv;
    const float* enc_state; ull* h0hist; ull* h1hist; float* h0buf; float* h1buf;
    const int* cs; const int* sos; const int* tgt; const float* emb;
    float* e_enc; float* e_dec;
    const float* outW; unsigned short* owbf; int doOut;
};
__global__ __launch_bounds__(256) void prep_kernel(PrepArgs g) {
    int bid = blockIdx.x, tid = threadIdx.x;
    if (bid < 9216) {
        if (!g.doConv) return;
        int m = bid / 1536, bx = bid - m * 1536;
        const float* src = g.src[m];
        unsigned short* dst = g.dst0 + (size_t)m * ((size_t)H3 * H);
        int i = (bx * 256 + tid) * 8;
        float4 a = *(const float4*)(src + i);
        float4 b = *(const float4*)(src + i + 4);
        us8 o;
        o[0] = f2bf_rne(a.x); o[1] = f2bf_rne(a.y); o[2] = f2bf_rne(a.z); o[3] = f2bf_rne(a.w);
        o[4] = f2bf_rne(b.x); o[5] = f2bf_rne(b.y); o[6] = f2bf_rne(b.z); o[7] = f2bf_rne(b.w);
        *(us8*)(dst + i) = o;
    } else if (bid < 9732) {
        int i = (bid - 9216) * 256 + tid;
        if (i >= NPH * 1024) return;
        ull v0 = 0, v1 = 0;
        if (i < 1024) {
            v0 = packh(g.enc_state[i]);
            v1 = packh(g.enc_state[H + i]);
            g.h0buf[i] = g.enc_state[i];
            g.h1buf[H + i] = g.enc_state[H + i];
        }
        g.h0hist[i] = v0;
        g.h1hist[i] = v1;
    } else if (bid < 9860) {
        int t = bid - 9732;   // 0..127
        int id;
        float* dst;
        if (t < SEQ) { id = g.cs[t]; dst = g.e_enc + (size_t)t * EMB; }
        else         { int td = t - SEQ; id = (td == 0) ? g.sos[0] : g.tgt[td - 1]; dst = g.e_dec + (size_t)td * EMB; }
        ((float2*)dst)[tid] = ((const float2*)(g.emb + (size_t)id * EMB))[tid];
    } else {
        if (!g.doOut) return;
        long long i = ((long long)(bid - 9860) * 256 + tid) * 8;   // < 10,240,000
        float4 a = *(const float4*)(g.outW + i);
        float4 b = *(const float4*)(g.outW + i + 4);
        us8 o;
        o[0] = f2bf_rne(a.x); o[1] = f2bf_rne(a.y); o[2] = f2bf_rne(a.z); o[3] = f2bf_rne(a.w);
        o[4] = f2bf_rne(b.x); o[5] = f2bf_rne(b.y); o[6] = f2bf_rne(b.z); o[7] = f2bf_rne(b.w);
        *(us8*)(g.owbf + i) = o;
    }
}

// ---------------- gi0 as tiled GEMM, batched over {enc,dec}: out = e @ W.T + b ----------------
__global__ __launch_bounds__(256) void gi_gemm_kernel(const float* __restrict__ Ae, const float* __restrict__ We,
                                                      const float* __restrict__ be, float* __restrict__ oe,
                                                      const float* __restrict__ Ad, const float* __restrict__ Wd,
                                                      const float* __restrict__ bd, float* __restrict__ od) {
    __shared__ float As[64][64 + 1];
    __shared__ float Bs[64][64 + 1];
    const float* A = blockIdx.y ? Ad : Ae;
    const float* W = blockIdx.y ? Wd : We;
    const float* bias = blockIdx.y ? bd : be;
    float* out = blockIdx.y ? od : oe;
    int n0 = blockIdx.x * 64;
    int tid = threadIdx.x;
    int tn = tid & 15, tm = tid >> 4;
    float acc[4][4] = {};
    for (int k0 = 0; k0 < EMB; k0 += 64) {
        for (int i = tid; i < 64 * 16; i += 256) {
            int m = i >> 4, kq = i & 15;
            float4 v = *(const float4*)(A + (size_t)m * EMB + k0 + kq * 4);
            As[kq * 4 + 0][m] = v.x; As[kq * 4 + 1][m] = v.y;
            As[kq * 4 + 2][m] = v.z; As[kq * 4 + 3][m] = v.w;
        }
        for (int i = tid; i < 64 * 16; i += 256) {
            int n = i >> 4, kq = i & 15;
            float4 v = *(const float4*)(W + (size_t)(n0 + n) * EMB + k0 + kq * 4);
            Bs[kq * 4 + 0][n] = v.x; Bs[kq * 4 + 1][n] = v.y;
            Bs[kq * 4 + 2][n] = v.z; Bs[kq * 4 + 3][n] = v.w;
        }
        __syncthreads();
        #pragma unroll 8
        for (int k = 0; k < 64; ++k) {
            float a[4], b[4];
            #pragma unroll
            for (int i = 0; i < 4; ++i) a[i] = As[k][tm * 4 + i];
            #pragma unroll
            for (int j = 0; j < 4; ++j) b[j] = Bs[k][tn * 4 + j];
            #pragma unroll
            for (int i = 0; i < 4; ++i)
                #pragma unroll
                for (int j = 0; j < 4; ++j) acc[i][j] += a[i] * b[j];
        }
        __syncthreads();
    }
    #pragma unroll
    for (int i = 0; i < 4; ++i) {
        int m = tm * 4 + i;
        #pragma unroll
        for (int j = 0; j < 4; ++j) {
            int r = n0 + tn * 4 + j;
            out[(size_t)m * H3 + r] = acc[i][j] + bias[r];
        }
    }
}

// ================= persistent recurrence kernel (v10: R10 dataflow + LDS double-buffer, fewer syncs) ==========
// 192 blocks x 1024 threads. Blocks 0..63 = A (layer0); 64..191 = B (layer1).
// h values flow through write-once (value,tag) 8B slots; relaxed agent atomics; no grid barrier.
// LDS staging ping-pongs on p&1 so the trailing per-phase __syncthreads is removed (A: 1 sync/phase,
// B: 2). sred stays single-buffered: next writes are gated by the next stage-sync.
// R11/R12: never fuse a bandwidth consumer into this kernel.
struct PArgs {
    const unsigned short *encWhh0, *encWih1, *encWhh1;
    const unsigned short *decWhh0, *decWih1, *decWhh1;
    const float *gi_enc0, *gi_dec0;
    const float *enc_bhh0, *dec_bhh0;
    const float *enc_bih1, *enc_bhh1, *dec_bih1, *dec_bhh1;
    ull *h0hist, *h1hist;
    float *states;
};

__device__ __forceinline__ void loadw24(const unsigned short* __restrict__ m,
                                        int j, int lane,
                                        u32x8& w0, u32x8& w1, u32x8& w2) {
    size_t b0 = (size_t)j * H + lane;
    size_t b1 = (size_t)(H + j) * H + lane;
    size_t b2 = (size_t)(2 * H + j) * H + lane;
    #pragma unroll
    for (int q = 0; q < 8; ++q) {
        w0[q] = (unsigned)m[b0 + 128 * q] | ((unsigned)m[b0 + 128 * q + 64] << 16);
        w1[q] = (unsigned)m[b1 + 128 * q] | ((unsigned)m[b1 + 128 * q + 64] << 16);
        w2[q] = (unsigned)m[b2 + 128 * q] | ((unsigned)m[b2 + 128 * q + 64] << 16);
    }
}

__global__ __launch_bounds__(1024, 4) void persist_kernel(PArgs a) {
    __shared__ __align__(16) float xh0[2][H];
    __shared__ __align__(16) float xh1[2][H];
    __shared__ float sred[64];
    const int tid = threadIdx.x;
    const int w = tid >> 6, lane = tid & 63;
    const int bid = blockIdx.x;

    if (bid < 64) {
        // ================= A: layer0, phases 0..127 =================
        const int j = bid * 16 + w;
        u32x8 w0, w1, w2;
        loadw24(a.encWhh0, j, lane, w0, w1, w2);
        float b0 = 0.f, b1 = 0.f, b2 = 0.f, g0 = 0.f, g1 = 0.f, g2 = 0.f;
        if (lane == 0) {
            b0 = a.enc_bhh0[j]; b1 = a.enc_bhh0[H + j]; b2 = a.enc_bhh0[2 * H + j];
            g0 = a.gi_enc0[j];  g1 = a.gi_enc0[H + j];  g2 = a.gi_enc0[2 * H + j];
        }
        for (int p = 0; p < 128; ++p) {
            float* xb = xh0[p & 1];
            {
                const ull* src = a.h0hist + (size_t)p * 1024 + tid;
                ull v = __hip_atomic_load(src, __ATOMIC_RELAXED, __HIP_MEMORY_SCOPE_AGENT);
                while (!(v >> 32)) {
                    __builtin_amdgcn_s_sleep(1);
                    v = __hip_atomic_load(src, __ATOMIC_RELAXED, __HIP_MEMORY_SCOPE_AGENT);
                }
                xb[tid] = __uint_as_float((unsigned)v);
            }
            __syncthreads();
            float s0 = 0.f, s1 = 0.f, s2 = 0.f;
            #pragma unroll
            for (int q = 0; q < 8; ++q) {
                float x0 = xb[lane + 128 * q];
                float x1 = xb[lane + 128 * q + 64];
                s0 += lof(w0[q]) * x0 + hif(w0[q]) * x1;
                s1 += lof(w1[q]) * x0 + hif(w1[q]) * x1;
                s2 += lof(w2[q]) * x0 + hif(w2[q]) * x1;
            }
            #pragma unroll
            for (int m = 1; m < 64; m <<= 1) {
                s0 += __shfl_xor(s0, m);
                s1 += __shfl_xor(s1, m);
                s2 += __shfl_xor(s2, m);
            }
            if (lane == 0) {
                float r = sigmoidf_(g0 + s0 + b0);
                float z = sigmoidf_(g1 + s1 + b1);
                float n = tanhf(g2 + r * (s2 + b2));
                float hn = (1.f - z) * n + z * xb[j];
                __hip_atomic_store(a.h0hist + (size_t)(p + 1) * 1024 + j, packh(hn),
                                   __ATOMIC_RELAXED, __HIP_MEMORY_SCOPE_AGENT);
                if (p >= 64) a.states[(size_t)(p - 64) * 2048 + j] = hn;
                if (p < 127) {
                    const float* gn = (p + 1 < 64) ? (a.gi_enc0 + (size_t)(p + 1) * H3)
                                                   : (a.gi_dec0 + (size_t)(p + 1 - 64) * H3);
                    g0 = gn[j]; g1 = gn[H + j]; g2 = gn[2 * H + j];
                }
            }
            if (p == 63) {
                loadw24(a.decWhh0, j, lane, w0, w1, w2);
                if (lane == 0) { b0 = a.dec_bhh0[j]; b1 = a.dec_bhh0[H + j]; b2 = a.dec_bhh0[2 * H + j]; }
            }
            // no trailing sync: next phase stages into the other buffer
        }
    } else {
        // ================= B: layer1, phases 1..128 =================
        const int bb = bid - 64;
        const int j = bb * 8 + (w >> 1);
        const int part = w & 1;   // 0: Wih1 rows (input = h0), 1: Whh1 rows (input = h1)
        u32x8 w0, w1, w2;
        loadw24(part == 0 ? a.encWih1 : a.encWhh1, j, lane, w0, w1, w2);
        float b0 = 0.f, b1 = 0.f, b2 = 0.f, b3 = 0.f, b4 = 0.f, b5 = 0.f;
        if (tid < 8) {
            int jg = bb * 8 + tid;
            b0 = a.enc_bih1[jg]; b1 = a.enc_bih1[H + jg]; b2 = a.enc_bih1[2 * H + jg];
            b3 = a.enc_bhh1[jg]; b4 = a.enc_bhh1[H + jg]; b5 = a.enc_bhh1[2 * H + jg];
        }
        for (int p = 1; p <= 128; ++p) {
            float* x0b = xh0[p & 1];
            float* x1b = xh1[p & 1];
            {
                const ull* s0p = a.h0hist + (size_t)p * 1024 + tid;
                const ull* s1p = a.h1hist + (size_t)(p - 1) * 1024 + tid;
                ull v0 = __hip_atomic_load(s0p, __ATOMIC_RELAXED, __HIP_MEMORY_SCOPE_AGENT);
                ull v1 = __hip_atomic_load(s1p, __ATOMIC_RELAXED, __HIP_MEMORY_SCOPE_AGENT);
                while (!(v0 >> 32) || !(v1 >> 32)) {
                    __builtin_amdgcn_s_sleep(1);
                    if (!(v0 >> 32)) v0 = __hip_atomic_load(s0p, __ATOMIC_RELAXED, __HIP_MEMORY_SCOPE_AGENT);
                    if (!(v1 >> 32)) v1 = __hip_atomic_load(s1p, __ATOMIC_RELAXED, __HIP_MEMORY_SCOPE_AGENT);
                }
                x0b[tid] = __uint_as_float((unsigned)v0);
                x1b[tid] = __uint_as_float((unsigned)v1);
            }
            __syncthreads();
            {
                const float* x = (part == 0) ? x0b : x1b;
                float s0 = 0.f, s1 = 0.f, s2 = 0.f;
                #pragma unroll
                for (int q = 0; q < 8; ++q) {
                    float x0 = x[lane + 128 * q];
                    float x1 = x[lane + 128 * q + 64];
                    s0 += lof(w0[q]) * x0 + hif(w0[q]) * x1;
                    s1 += lof(w1[q]) * x0 + hif(w1[q]) * x1;
                    s2 += lof(w2[q]) * x0 + hif(w2[q]) * x1;
                }
                #pragma unroll
                for (int m = 1; m < 64; m <<= 1) {
                    s0 += __shfl_xor(s0, m);
                    s1 += __shfl_xor(s1, m);
                    s2 += __shfl_xor(s2, m);
                }
                if (lane == 0) {
                    int slot = (w >> 1) * 8 + part * 4;
                    sred[slot + 0] = s0; sred[slot + 1] = s1; sred[slot + 2] = s2;
                }
            }
            __syncthreads();
            if (tid < 8) {
                int jg = bb * 8 + tid;
                float si0 = sred[tid * 8 + 0], si1 = sred[tid * 8 + 1], si2 = sred[tid * 8 + 2];
                float sh0 = sred[tid * 8 + 4], sh1 = sred[tid * 8 + 5], sh2 = sred[tid * 8 + 6];
                float r = sigmoidf_(si0 + b0 + sh0 + b3);
                float z = sigmoidf_(si1 + b1 + sh1 + b4);
                float n = tanhf(si2 + b2 + r * (sh2 + b5));
                float hn = (1.f - z) * n + z * x1b[jg];
                __hip_atomic_store(a.h1hist + (size_t)p * 1024 + jg, packh(hn),
                                   __ATOMIC_RELAXED, __HIP_MEMORY_SCOPE_AGENT);
                if (p >= 65) a.states[(size_t)(p - 65) * 2048 + H + jg] = hn;
            }
            if (p == 64) {
                loadw24(part == 0 ? a.decWih1 : a.decWhh1, j, lane, w0, w1, w2);
                if (tid < 8) {
                    int jg = bb * 8 + tid;
                    b0 = a.dec_bih1[jg]; b1 = a.dec_bih1[H + jg]; b2 = a.dec_bih1[2 * H + jg];
                    b3 = a.dec_bhh1[jg]; b4 = a.dec_bhh1[H + jg]; b5 = a.dec_bhh1[2 * H + jg];
                }
            }
            // no trailing sync: double-buffered staging
        }
    }
}

// ---------------- fallback per-phase kernel (only if cooperative launch fails) ----------------
template<int BF>
__global__ __launch_bounds__(384) void phase_kernel(
    const float* __restrict__ giA, const void* __restrict__ WhhA, const float* __restrict__ bhhA,
    const float* __restrict__ h0r, float* __restrict__ h0w, float* __restrict__ statesA, int hasA,
    const void* __restrict__ WihB, const float* __restrict__ bihB,
    const void* __restrict__ WhhB, const float* __restrict__ bhhB,
    const float* __restrict__ h1r, float* __restrict__ h1w, float* __restrict__ statesB, int hasB) {
    __shared__ float sred[8];
    int bid = blockIdx.x;
    int tid = threadIdx.x;
    int w = tid >> 6, lane = tid & 63;
    auto dotf = [&](const void* Wp, size_t roff, const float* x) -> float {
        float s = 0.f;
        if (BF) {
            const unsigned short* wrow = (const unsigned short*)Wp + roff;
            #pragma unroll
            for (int i = 0; i < 2; ++i) {
                int k = lane * 8 + i * 512;
                us8 wv = *(const us8*)(wrow + k);
                float4 x0 = *(const float4*)(x + k);
                float4 x1 = *(const float4*)(x + k + 4);
                s += bf2f(wv[0]) * x0.x + bf2f(wv[1]) * x0.y + bf2f(wv[2]) * x0.z + bf2f(wv[3]) * x0.w
                   + bf2f(wv[4]) * x1.x + bf2f(wv[5]) * x1.y + bf2f(wv[6]) * x1.z + bf2f(wv[7]) * x1.w;
            }
        } else {
            const float* wrow = (const float*)Wp + roff;
            #pragma unroll
            for (int i = 0; i < 4; ++i) {
                int k = lane * 4 + i * 256;
                float4 wv = *(const float4*)(wrow + k);
                float4 xv = *(const float4*)(x + k);
                s += wv.x * xv.x + wv.y * xv.y + wv.z * xv.z + wv.w * xv.w;
            }
        }
        return s;
    };
    if (bid < 512) {
        if (!hasA) return;
        int tt = w / 3, g = w - tt * 3;
        int jj = bid * 2 + tt;
        float s = dotf(WhhA, (size_t)(g * H + jj) * H, h0r);
        #pragma unroll
        for (int m = 1; m < 64; m <<= 1) s += __shfl_xor(s, m);
        if (lane == 0) sred[w] = s;
        __syncthreads();
        if (tid < 2) {
            int j2 = bid * 2 + tid;
            float s0 = sred[tid * 3], s1 = sred[tid * 3 + 1], s2 = sred[tid * 3 + 2];
            float r = sigmoidf_(giA[j2] + s0 + bhhA[j2]);
            float z = sigmoidf_(giA[H + j2] + s1 + bhhA[H + j2]);
            float n = tanhf(giA[2 * H + j2] + r * (s2 + bhhA[2 * H + j2]));
            float hn = (1.f - z) * n + z * h0r[j2];
            h0w[j2] = hn;
            if (statesA) statesA[j2] = hn;
        }
    } else {
        if (!hasB) return;
        int j = bid - 512;
        int hh = (w >= 3);
        int g = w - hh * 3;
        float s = dotf(hh ? WhhB : WihB, (size_t)(g * H + j) * H, hh ? h1r : h0r);
        #pragma unroll
        for (int m = 1; m < 64; m <<= 1) s += __shfl_xor(s, m);
        if (lane == 0) sred[w] = s;
        __syncthreads();
        if (tid == 0) {
            float r = sigmoidf_(sred[0] + bihB[j] + sred[3] + bhhB[j]);
            float z = sigmoidf_(sred[1] + bihB[H + j] + sred[4] + bhhB[H + j]);
            float n = tanhf(sred[2] + bihB[2 * H + j] + r * (sred[5] + bhhB[2 * H + j]));
            float hn = (1.f - z) * n + z * h1r[j];
            h1w[j] = hn;
            if (statesB) statesB[j] = hn;
        }
    }
}

// ---------------- scores GEMM, split-K (templated f32/bf16 weights; BF path verified R3-R5) ----------------
#define SN 64
#define SK 64
template<int BF>
__global__ __launch_bounds__(256) void scores_kernel(const float* __restrict__ states,
                                                     const void* __restrict__ W,
                                                     const float* __restrict__ bias,
                                                     float* __restrict__ dst, int kc_count) {
    __shared__ float As[SK][64 + 1];
    __shared__ float Bs[SK][SN + 1];
    int n0 = blockIdx.x * SN;
    int kc = blockIdx.y;
    int klen = H / kc_count;
    int kbeg = kc * klen;
    int tid = threadIdx.x;
    int tn = tid & 15, tm = tid >> 4;
    float acc[4][4] = {};
    for (int k0 = kbeg; k0 < kbeg + klen; k0 += SK) {
        for (int i = tid; i < 64 * (SK / 4); i += 256) {
            int m = i >> 4;
            int kq = i & 15;
            float4 v = *(const float4*)(states + (size_t)m * 2048 + H + k0 + kq * 4);
            As[kq * 4 + 0][m] = v.x; As[kq * 4 + 1][m] = v.y;
            As[kq * 4 + 2][m] = v.z; As[kq * 4 + 3][m] = v.w;
        }
        if (BF) {
            for (int i = tid; i < SN * (SK / 8); i += 256) {
                int n = i >> 3;
                int ko = (i & 7) * 8;
                int r = n0 + n;
                if (r < V) {
                    us8 v = *(const us8*)((const unsigned short*)W + (size_t)r * H + k0 + ko);
                    #pragma unroll
                    for (int d = 0; d < 8; ++d) Bs[ko + d][n] = bf2f(v[d]);
                } else {
                    #pragma unroll
                    for (int d = 0; d < 8; ++d) Bs[ko + d][n] = 0.f;
                }
            }
        } else {
            for (int i = tid; i < SN * (SK / 4); i += 256) {
                int n = i >> 4;
                int kq = i & 15;
                int r = n0 + n;
                float4 v = make_float4(0.f, 0.f, 0.f, 0.f);
                if (r < V) v = *(const float4*)((const float*)W + (size_t)r * H + k0 + kq * 4);
                Bs[kq * 4 + 0][n] = v.x; Bs[kq * 4 + 1][n] = v.y;
                Bs[kq * 4 + 2][n] = v.z; Bs[kq * 4 + 3][n] = v.w;
            }
        }
        __syncthreads();
        #pragma unroll 8
        for (int k = 0; k < SK; ++k) {
            float a[4], b[4];
            #pragma unroll
            for (int i = 0; i < 4; ++i) a[i] = As[k][tm * 4 + i];
            #pragma unroll
            for (int j = 0; j < 4; ++j) b[j] = Bs[k][tn * 4 + j];
            #pragma unroll
            for (int i = 0; i < 4; ++i)
                #pragma unroll
                for (int j = 0; j < 4; ++j) acc[i][j] += a[i] * b[j];
        }
        __syncthreads();
    }
    if (kc_count == 1) {
        #pragma unroll
        for (int i = 0; i < 4; ++i) {
            int m = tm * 4 + i;
            #pragma unroll
            for (int j = 0; j < 4; ++j) {
                int r = n0 + tn * 4 + j;
                if (r < V) dst[(size_t)m * V + r] = acc[i][j] + bias[r];
            }
        }
    } else {
        #pragma unroll
        for (int i = 0; i < 4; ++i) {
            int m = tm * 4 + i;
            #pragma unroll
            for (int j = 0; j < 4; ++j) {
                int r = n0 + tn * 4 + j;
                dst[(size_t)(kc * 64 + m) * NPAD + r] = acc[i][j];
            }
        }
    }
}

__global__ __launch_bounds__(256) void reduce_scores_kernel(const float* __restrict__ part,
                                                            const float* __restrict__ bias,
                                                            float* __restrict__ out, int kc_count) {
    int e = blockIdx.x * 256 + threadIdx.x;
    if (e >= 64 * V) return;
    int m = e / V, r = e - m * V;
    float s = bias[r];
    for (int kc = 0; kc < kc_count; ++kc)
        s += part[(size_t)(kc * 64 + m) * NPAD + r];
    out[(size_t)m * V + r] = s;
}

extern "C" void kernel_launch(void* const* d_in, const int* in_sizes, int n_in,
                              void* d_out, int out_size, void* d_ws, size_t ws_size,
                              hipStream_t stream) {
    const int*   char_seq  = (const int*)d_in[0];
    const float* enc_state = (const float*)d_in[1];
    const int*   sos       = (const int*)d_in[2];
    const int*   tgt       = (const int*)d_in[5];
    const float* emb       = (const float*)d_in[6];
    const float* enc_Wih0  = (const float*)d_in[7];
    const float* enc_Whh0  = (const float*)d_in[8];
    const float* enc_bih0  = (const float*)d_in[9];
    const float* enc_bhh0  = (const float*)d_in[10];
    const float* enc_Wih1  = (const float*)d_in[11];
    const float* enc_Whh1  = (const float*)d_in[12];
    const float* enc_bih1  = (const float*)d_in[13];
    const float* enc_bhh1  = (const float*)d_in[14];
    const float* dec_Wih0  = (const float*)d_in[15];
    const float* dec_Whh0  = (const float*)d_in[16];
    const float* dec_bih0  = (const float*)d_in[17];
    const float* dec_bhh0  = (const float*)d_in[18];
    const float* dec_Wih1  = (const float*)d_in[19];
    const float* dec_Whh1  = (const float*)d_in[20];
    const float* dec_bih1  = (const float*)d_in[21];
    const float* dec_bhh1  = (const float*)d_in[22];
    const float* out_W     = (const float*)d_in[23];
    const float* out_b     = (const float*)d_in[24];

    float* ws = (float*)d_ws;
    float* e_enc   = ws;                       // 64*512
    float* e_dec   = e_enc + SEQ * EMB;        // 64*512
    float* gi_enc0 = e_dec + SEQ * EMB;        // 64*3072
    float* gi_dec0 = gi_enc0 + SEQ * H3;       // 64*3072
    ull*   h0hist  = (ull*)(gi_dec0 + SEQ * H3);        // NPH*1024 ull
    ull*   h1hist  = h0hist + (size_t)NPH * 1024;       // NPH*1024 ull
    float* h0buf   = (float*)(h1hist + (size_t)NPH * 1024);  // 2*1024 (fallback)
    float* h1buf   = h0buf + 2 * H;                          // 2*1024 (fallback)
    float* cur     = h1buf + 2 * H;
    size_t base = (size_t)(cur - ws);
    size_t avail = ws_size / 4 > base ? ws_size / 4 - base : 0;

    const size_t REC_ELEMS = (size_t)H3 * H;   // per matrix
    const size_t REC_SLOTS = REC_ELEMS / 2;    // float-slots per bf16 matrix
    const size_t OUT_ELEMS = (size_t)V * H;
    const size_t OUT_SLOTS = OUT_ELEMS / 2;

    int bf_rec = (avail >= 6 * REC_SLOTS);
    unsigned short* wbf0 = nullptr;
    if (bf_rec) { wbf0 = (unsigned short*)cur; cur += 6 * REC_SLOTS; avail -= 6 * REC_SLOTS; }
    int bf_out = (avail >= OUT_SLOTS);
    unsigned short* owbf = nullptr;
    if (bf_out) { owbf = (unsigned short*)cur; cur += OUT_SLOTS; avail -= OUT_SLOTS; }
    int KC = 1;
    if (avail >= (size_t)8 * 64 * NPAD) KC = 8;
    else if (avail >= (size_t)4 * 64 * NPAD) KC = 4;
    else if (avail >= (size_t)2 * 64 * NPAD) KC = 2;
    float* partials = cur;

    float* scores = (float*)d_out;             // 64*10000
    float* states = scores + SEQ * V;          // 64*2048

    // ---- merged prep: conversions + history init + embedding ----
    PrepArgs pg;
    pg.src[0] = enc_Whh0; pg.src[1] = enc_Wih1; pg.src[2] = enc_Whh1;
    pg.src[3] = dec_Whh0; pg.src[4] = dec_Wih1; pg.src[5] = dec_Whh1;
    pg.dst0 = wbf0; pg.doConv = bf_rec;
    pg.enc_state = enc_state; pg.h0hist = h0hist; pg.h1hist = h1hist;
    pg.h0buf = h0buf; pg.h1buf = h1buf;
    pg.cs = char_seq; pg.sos = sos; pg.tgt = tgt; pg.emb = emb;
    pg.e_enc = e_enc; pg.e_dec = e_dec;
    pg.outW = out_W; pg.owbf = owbf; pg.doOut = bf_out;
    prep_kernel<<<14860, 256, 0, stream>>>(pg);
    gi_gemm_kernel<<<dim3(H3 / 64, 2), 256, 0, stream>>>(e_enc, enc_Wih0, enc_bih0, gi_enc0,
                                                         e_dec, dec_Wih0, dec_bih0, gi_dec0);

    bool done = false;
    if (bf_rec) {
        PArgs pa;
        pa.encWhh0 = wbf0;
        pa.encWih1 = wbf0 + REC_ELEMS;
        pa.encWhh1 = wbf0 + 2 * REC_ELEMS;
        pa.decWhh0 = wbf0 + 3 * REC_ELEMS;
        pa.decWih1 = wbf0 + 4 * REC_ELEMS;
        pa.decWhh1 = wbf0 + 5 * REC_ELEMS;
        pa.gi_enc0 = gi_enc0; pa.gi_dec0 = gi_dec0;
        pa.enc_bhh0 = enc_bhh0; pa.dec_bhh0 = dec_bhh0;
        pa.enc_bih1 = enc_bih1; pa.enc_bhh1 = enc_bhh1;
        pa.dec_bih1 = dec_bih1; pa.dec_bhh1 = dec_bhh1;
        pa.h0hist = h0hist; pa.h1hist = h1hist; pa.states = states;
        void* kparams[] = { (void*)&pa };
        hipError_t err = hipLaunchCooperativeKernel((const void*)persist_kernel,
                                                    dim3(192), dim3(1024), kparams, 0, stream);
        done = (err == hipSuccess);
    }

    if (!done) {
        for (int p = 0; p <= 128; ++p) {
            int hasA = (p <= 127);
            int hasB = (p >= 1);
            const float* giA = nullptr; const void* WhhA = nullptr; const float* bhhA = nullptr;
            float* statesA = nullptr;
            if (hasA) {
                if (p < 64) {
                    giA = gi_enc0 + (size_t)p * H3; bhhA = enc_bhh0;
                    WhhA = bf_rec ? (const void*)wbf0 : (const void*)enc_Whh0;
                } else {
                    int t = p - 64;
                    giA = gi_dec0 + (size_t)t * H3; bhhA = dec_bhh0;
                    WhhA = bf_rec ? (const void*)(wbf0 + 3 * REC_ELEMS) : (const void*)dec_Whh0;
                    statesA = states + (size_t)t * 2048;
                }
            }
            const void *WihB = nullptr, *WhhB = nullptr;
            const float *bihB = nullptr, *bhhB = nullptr;
            float* statesB = nullptr;
            if (hasB) {
                if (p <= 64) {
                    bihB = enc_bih1; bhhB = enc_bhh1;
                    WihB = bf_rec ? (const void*)(wbf0 + REC_ELEMS) : (const void*)enc_Wih1;
                    WhhB = bf_rec ? (const void*)(wbf0 + 2 * REC_ELEMS) : (const void*)enc_Whh1;
                } else {
                    int t = p - 65;
                    bihB = dec_bih1; bhhB = dec_bhh1;
                    WihB = bf_rec ? (const void*)(wbf0 + 4 * REC_ELEMS) : (const void*)dec_Wih1;
                    WhhB = bf_rec ? (const void*)(wbf0 + 5 * REC_ELEMS) : (const void*)dec_Whh1;
                    statesB = states + (size_t)t * 2048 + H;
                }
            }
            float* h0r = h0buf + (p & 1) * H;
            float* h0w = h0buf + ((p + 1) & 1) * H;
            float* h1r = h1buf + (p & 1) * H;
            float* h1w = h1buf + ((p + 1) & 1) * H;
            if (bf_rec)
                phase_kernel<1><<<1536, 384, 0, stream>>>(giA, WhhA, bhhA, h0r, h0w, statesA, hasA,
                                                          WihB, bihB, WhhB, bhhB, h1r, h1w, statesB, hasB);
            else
                phase_kernel<0><<<1536, 384, 0, stream>>>(giA, WhhA, bhhA, h0r, h0w, statesA, hasA,
                                                          WihB, bihB, WhhB, bhhB, h1r, h1w, statesB, hasB);
        }
    }

    const void* Wsc = bf_out ? (const void*)owbf : (const void*)out_W;
    if (KC == 1) {
        if (bf_out)
            scores_kernel<1><<<dim3((V + SN - 1) / SN, 1), 256, 0, stream>>>(states, Wsc, out_b, scores, 1);
        else
            scores_kernel<0><<<dim3((V + SN - 1) / SN, 1), 256, 0, stream>>>(states, Wsc, out_b, scores, 1);
    } else {
        if (bf_out)
            scores_kernel<1><<<dim3((V + SN - 1) / SN, KC), 256, 0, stream>>>(states, Wsc, out_b, partials, KC);
        else
            scores_kernel<0><<<dim3((V + SN - 1) / SN, KC), 256, 0, stream>>>(states, Wsc, out_b, partials, KC);
        reduce_scores_kernel<<<(64 * V + 255) / 256, 256, 0, stream>>>(partials, out_b, scores, KC);
    }
}

// Round 15
// 529.110 us; speedup vs baseline: 1.3727x; 1.3727x over previous
//
#include <hip/hip_runtime.h>
#include <hip/hip_bf16.h>
#include <math.h>

#define V     10000
#define EMB   512
#define H     1024
#define H3    3072
#define SEQ   64
#define NPAD  10048   // padded N for score partials
#define NPH   129     // history slots (phases 0..128)

typedef __attribute__((ext_vector_type(8))) unsigned short us8;
typedef __attribute__((ext_vector_type(8))) unsigned u32x8;
typedef unsigned long long ull;

__device__ __forceinline__ float sigmoidf_(float x) { return 1.0f / (1.0f + expf(-x)); }
__device__ __forceinline__ float bf2f(unsigned short u) { return __uint_as_float(((unsigned)u) << 16); }
__device__ __forceinline__ float lof(unsigned u) { return __uint_as_float(u << 16); }
__device__ __forceinline__ float hif(unsigned u) { return __uint_as_float(u & 0xffff0000u); }
__device__ __forceinline__ unsigned short f2bf_rne(float f) {
    unsigned u = __float_as_uint(f);
    unsigned r = u + 0x7FFF + ((u >> 16) & 1);
    return (unsigned short)(r >> 16);
}
__device__ __forceinline__ ull packh(float v) {
    return (ull)__float_as_uint(v) | (1ULL << 32);
}

// ---------------- merged prep: weight conversion + history init + embedding ----------------
// grid.x = 9216 (conv: 6 matrices x 1536) + 516 (init) + 128 (embed), 256 threads
struct PrepArgs {
    const float* src[6]; unsigned short* dst0; int doConv;
    const float* enc_state; ull* h0hist; ull* h1hist; float* h0buf; float* h1buf;
    const int* cs; const int* sos; const int* tgt; const float* emb;
    float* e_enc; float* e_dec;
};
__global__ __launch_bounds__(256) void prep_kernel(PrepArgs g) {
    int bid = blockIdx.x, tid = threadIdx.x;
    if (bid < 9216) {
        if (!g.doConv) return;
        int m = bid / 1536, bx = bid - m * 1536;
        const float* src = g.src[m];
        unsigned short* dst = g.dst0 + (size_t)m * ((size_t)H3 * H);
        int i = (bx * 256 + tid) * 8;
        float4 a = *(const float4*)(src + i);
        float4 b = *(const float4*)(src + i + 4);
        us8 o;
        o[0] = f2bf_rne(a.x); o[1] = f2bf_rne(a.y); o[2] = f2bf_rne(a.z); o[3] = f2bf_rne(a.w);
        o[4] = f2bf_rne(b.x); o[5] = f2bf_rne(b.y); o[6] = f2bf_rne(b.z); o[7] = f2bf_rne(b.w);
        *(us8*)(dst + i) = o;
    } else if (bid < 9732) {
        int i = (bid - 9216) * 256 + tid;
        if (i >= NPH * 1024) return;
        ull v0 = 0, v1 = 0;
        if (i < 1024) {
            v0 = packh(g.enc_state[i]);
            v1 = packh(g.enc_state[H + i]);
            g.h0buf[i] = g.enc_state[i];
            g.h1buf[H + i] = g.enc_state[H + i];
        }
        g.h0hist[i] = v0;
        g.h1hist[i] = v1;
    } else {
        int t = bid - 9732;   // 0..127
        int id;
        float* dst;
        if (t < SEQ) { id = g.cs[t]; dst = g.e_enc + (size_t)t * EMB; }
        else         { int td = t - SEQ; id = (td == 0) ? g.sos[0] : g.tgt[td - 1]; dst = g.e_dec + (size_t)td * EMB; }
        ((float2*)dst)[tid] = ((const float2*)(g.emb + (size_t)id * EMB))[tid];
    }
}

// ---------------- gi0 as tiled GEMM, batched over {enc,dec}: out = e @ W.T + b ----------------
__global__ __launch_bounds__(256) void gi_gemm_kernel(const float* __restrict__ Ae, const float* __restrict__ We,
                                                      const float* __restrict__ be, float* __restrict__ oe,
                                                      const float* __restrict__ Ad, const float* __restrict__ Wd,
                                                      const float* __restrict__ bd, float* __restrict__ od) {
    __shared__ float As[64][64 + 1];
    __shared__ float Bs[64][64 + 1];
    const float* A = blockIdx.y ? Ad : Ae;
    const float* W = blockIdx.y ? Wd : We;
    const float* bias = blockIdx.y ? bd : be;
    float* out = blockIdx.y ? od : oe;
    int n0 = blockIdx.x * 64;
    int tid = threadIdx.x;
    int tn = tid & 15, tm = tid >> 4;
    float acc[4][4] = {};
    for (int k0 = 0; k0 < EMB; k0 += 64) {
        for (int i = tid; i < 64 * 16; i += 256) {
            int m = i >> 4, kq = i & 15;
            float4 v = *(const float4*)(A + (size_t)m * EMB + k0 + kq * 4);
            As[kq * 4 + 0][m] = v.x; As[kq * 4 + 1][m] = v.y;
            As[kq * 4 + 2][m] = v.z; As[kq * 4 + 3][m] = v.w;
        }
        for (int i = tid; i < 64 * 16; i += 256) {
            int n = i >> 4, kq = i & 15;
            float4 v = *(const float4*)(W + (size_t)(n0 + n) * EMB + k0 + kq * 4);
            Bs[kq * 4 + 0][n] = v.x; Bs[kq * 4 + 1][n] = v.y;
            Bs[kq * 4 + 2][n] = v.z; Bs[kq * 4 + 3][n] = v.w;
        }
        __syncthreads();
        #pragma unroll 8
        for (int k = 0; k < 64; ++k) {
            float a[4], b[4];
            #pragma unroll
            for (int i = 0; i < 4; ++i) a[i] = As[k][tm * 4 + i];
            #pragma unroll
            for (int j = 0; j < 4; ++j) b[j] = Bs[k][tn * 4 + j];
            #pragma unroll
            for (int i = 0; i < 4; ++i)
                #pragma unroll
                for (int j = 0; j < 4; ++j) acc[i][j] += a[i] * b[j];
        }
        __syncthreads();
    }
    #pragma unroll
    for (int i = 0; i < 4; ++i) {
        int m = tm * 4 + i;
        #pragma unroll
        for (int j = 0; j < 4; ++j) {
            int r = n0 + tn * 4 + j;
            out[(size_t)m * H3 + r] = acc[i][j] + bias[r];
        }
    }
}

// ================= persistent recurrence kernel (R10-exact: barrier-free tagged dataflow) =================
// 192 blocks x 1024 threads. Blocks 0..63 = A (layer0): wave w -> j = bid*16+w, 3 gate rows
// in 24 packed VGPRs. Blocks 64..191 = B (layer1): j = (bid-64)*8+(w>>1); part = w&1.
// h values flow through write-once (value,tag) 8B slots; relaxed agent atomics; no barrier.
// R11/R12/R14 lessons: no fused bandwidth consumers; keep the trailing __syncthreads (it
// aligns each block's poll start to data readiness — removing it adds poll-retry traffic).
struct PArgs {
    const unsigned short *encWhh0, *encWih1, *encWhh1;
    const unsigned short *decWhh0, *decWih1, *decWhh1;
    const float *gi_enc0, *gi_dec0;
    const float *enc_bhh0, *dec_bhh0;
    const float *enc_bih1, *enc_bhh1, *dec_bih1, *dec_bhh1;
    ull *h0hist, *h1hist;
    float *states;
};

__device__ __forceinline__ void loadw24(const unsigned short* __restrict__ m,
                                        int j, int lane,
                                        u32x8& w0, u32x8& w1, u32x8& w2) {
    size_t b0 = (size_t)j * H + lane;
    size_t b1 = (size_t)(H + j) * H + lane;
    size_t b2 = (size_t)(2 * H + j) * H + lane;
    #pragma unroll
    for (int q = 0; q < 8; ++q) {
        w0[q] = (unsigned)m[b0 + 128 * q] | ((unsigned)m[b0 + 128 * q + 64] << 16);
        w1[q] = (unsigned)m[b1 + 128 * q] | ((unsigned)m[b1 + 128 * q + 64] << 16);
        w2[q] = (unsigned)m[b2 + 128 * q] | ((unsigned)m[b2 + 128 * q + 64] << 16);
    }
}

__global__ __launch_bounds__(1024, 4) void persist_kernel(PArgs a) {
    __shared__ __align__(16) float xh0[H];
    __shared__ __align__(16) float xh1[H];
    __shared__ float sred[64];
    const int tid = threadIdx.x;
    const int w = tid >> 6, lane = tid & 63;
    const int bid = blockIdx.x;

    if (bid < 64) {
        // ================= A: layer0, phases 0..127 =================
        const int j = bid * 16 + w;
        u32x8 w0, w1, w2;
        loadw24(a.encWhh0, j, lane, w0, w1, w2);
        float b0 = 0.f, b1 = 0.f, b2 = 0.f, g0 = 0.f, g1 = 0.f, g2 = 0.f;
        if (lane == 0) {
            b0 = a.enc_bhh0[j]; b1 = a.enc_bhh0[H + j]; b2 = a.enc_bhh0[2 * H + j];
            g0 = a.gi_enc0[j];  g1 = a.gi_enc0[H + j];  g2 = a.gi_enc0[2 * H + j];
        }
        for (int p = 0; p < 128; ++p) {
            {
                const ull* src = a.h0hist + (size_t)p * 1024 + tid;
                ull v = __hip_atomic_load(src, __ATOMIC_RELAXED, __HIP_MEMORY_SCOPE_AGENT);
                while (!(v >> 32)) {
                    __builtin_amdgcn_s_sleep(1);
                    v = __hip_atomic_load(src, __ATOMIC_RELAXED, __HIP_MEMORY_SCOPE_AGENT);
                }
                xh0[tid] = __uint_as_float((unsigned)v);
            }
            __syncthreads();
            float s0 = 0.f, s1 = 0.f, s2 = 0.f;
            #pragma unroll
            for (int q = 0; q < 8; ++q) {
                float x0 = xh0[lane + 128 * q];
                float x1 = xh0[lane + 128 * q + 64];
                s0 += lof(w0[q]) * x0 + hif(w0[q]) * x1;
                s1 += lof(w1[q]) * x0 + hif(w1[q]) * x1;
                s2 += lof(w2[q]) * x0 + hif(w2[q]) * x1;
            }
            #pragma unroll
            for (int m = 1; m < 64; m <<= 1) {
                s0 += __shfl_xor(s0, m);
                s1 += __shfl_xor(s1, m);
                s2 += __shfl_xor(s2, m);
            }
            if (lane == 0) {
                float r = sigmoidf_(g0 + s0 + b0);
                float z = sigmoidf_(g1 + s1 + b1);
                float n = tanhf(g2 + r * (s2 + b2));
                float hn = (1.f - z) * n + z * xh0[j];
                __hip_atomic_store(a.h0hist + (size_t)(p + 1) * 1024 + j, packh(hn),
                                   __ATOMIC_RELAXED, __HIP_MEMORY_SCOPE_AGENT);
                if (p >= 64) a.states[(size_t)(p - 64) * 2048 + j] = hn;
                if (p < 127) {
                    const float* gn = (p + 1 < 64) ? (a.gi_enc0 + (size_t)(p + 1) * H3)
                                                   : (a.gi_dec0 + (size_t)(p + 1 - 64) * H3);
                    g0 = gn[j]; g1 = gn[H + j]; g2 = gn[2 * H + j];
                }
            }
            if (p == 63) {
                loadw24(a.decWhh0, j, lane, w0, w1, w2);
                if (lane == 0) { b0 = a.dec_bhh0[j]; b1 = a.dec_bhh0[H + j]; b2 = a.dec_bhh0[2 * H + j]; }
            }
            __syncthreads();   // xh0 stable until all waves finish this phase
        }
    } else {
        // ================= B: layer1, phases 1..128 =================
        const int bb = bid - 64;
        const int j = bb * 8 + (w >> 1);
        const int part = w & 1;   // 0: Wih1 rows (input = h0), 1: Whh1 rows (input = h1)
        u32x8 w0, w1, w2;
        loadw24(part == 0 ? a.encWih1 : a.encWhh1, j, lane, w0, w1, w2);
        float b0 = 0.f, b1 = 0.f, b2 = 0.f, b3 = 0.f, b4 = 0.f, b5 = 0.f;
        if (tid < 8) {
            int jg = bb * 8 + tid;
            b0 = a.enc_bih1[jg]; b1 = a.enc_bih1[H + jg]; b2 = a.enc_bih1[2 * H + jg];
            b3 = a.enc_bhh1[jg]; b4 = a.enc_bhh1[H + jg]; b5 = a.enc_bhh1[2 * H + jg];
        }
        for (int p = 1; p <= 128; ++p) {
            {
                const ull* s0p = a.h0hist + (size_t)p * 1024 + tid;
                const ull* s1p = a.h1hist + (size_t)(p - 1) * 1024 + tid;
                ull v0 = __hip_atomic_load(s0p, __ATOMIC_RELAXED, __HIP_MEMORY_SCOPE_AGENT);
                ull v1 = __hip_atomic_load(s1p, __ATOMIC_RELAXED, __HIP_MEMORY_SCOPE_AGENT);
                while (!(v0 >> 32) || !(v1 >> 32)) {
                    __builtin_amdgcn_s_sleep(1);
                    if (!(v0 >> 32)) v0 = __hip_atomic_load(s0p, __ATOMIC_RELAXED, __HIP_MEMORY_SCOPE_AGENT);
                    if (!(v1 >> 32)) v1 = __hip_atomic_load(s1p, __ATOMIC_RELAXED, __HIP_MEMORY_SCOPE_AGENT);
                }
                xh0[tid] = __uint_as_float((unsigned)v0);
                xh1[tid] = __uint_as_float((unsigned)v1);
            }
            __syncthreads();
            {
                const float* x = (part == 0) ? xh0 : xh1;
                float s0 = 0.f, s1 = 0.f, s2 = 0.f;
                #pragma unroll
                for (int q = 0; q < 8; ++q) {
                    float x0 = x[lane + 128 * q];
                    float x1 = x[lane + 128 * q + 64];
                    s0 += lof(w0[q]) * x0 + hif(w0[q]) * x1;
                    s1 += lof(w1[q]) * x0 + hif(w1[q]) * x1;
                    s2 += lof(w2[q]) * x0 + hif(w2[q]) * x1;
                }
                #pragma unroll
                for (int m = 1; m < 64; m <<= 1) {
                    s0 += __shfl_xor(s0, m);
                    s1 += __shfl_xor(s1, m);
                    s2 += __shfl_xor(s2, m);
                }
                if (lane == 0) {
                    int slot = (w >> 1) * 8 + part * 4;
                    sred[slot + 0] = s0; sred[slot + 1] = s1; sred[slot + 2] = s2;
                }
            }
            __syncthreads();
            if (tid < 8) {
                int jg = bb * 8 + tid;
                float si0 = sred[tid * 8 + 0], si1 = sred[tid * 8 + 1], si2 = sred[tid * 8 + 2];
                float sh0 = sred[tid * 8 + 4], sh1 = sred[tid * 8 + 5], sh2 = sred[tid * 8 + 6];
                float r = sigmoidf_(si0 + b0 + sh0 + b3);
                float z = sigmoidf_(si1 + b1 + sh1 + b4);
                float n = tanhf(si2 + b2 + r * (sh2 + b5));
                float hn = (1.f - z) * n + z * xh1[jg];
                __hip_atomic_store(a.h1hist + (size_t)p * 1024 + jg, packh(hn),
                                   __ATOMIC_RELAXED, __HIP_MEMORY_SCOPE_AGENT);
                if (p >= 65) a.states[(size_t)(p - 65) * 2048 + H + jg] = hn;
            }
            if (p == 64) {
                loadw24(part == 0 ? a.decWih1 : a.decWhh1, j, lane, w0, w1, w2);
                if (tid < 8) {
                    int jg = bb * 8 + tid;
                    b0 = a.dec_bih1[jg]; b1 = a.dec_bih1[H + jg]; b2 = a.dec_bih1[2 * H + jg];
                    b3 = a.dec_bhh1[jg]; b4 = a.dec_bhh1[H + jg]; b5 = a.dec_bhh1[2 * H + jg];
                }
            }
            __syncthreads();
        }
    }
}

// ---------------- fallback per-phase kernel (only if cooperative launch fails) ----------------
template<int BF>
__global__ __launch_bounds__(384) void phase_kernel(
    const float* __restrict__ giA, const void* __restrict__ WhhA, const float* __restrict__ bhhA,
    const float* __restrict__ h0r, float* __restrict__ h0w, float* __restrict__ statesA, int hasA,
    const void* __restrict__ WihB, const float* __restrict__ bihB,
    const void* __restrict__ WhhB, const float* __restrict__ bhhB,
    const float* __restrict__ h1r, float* __restrict__ h1w, float* __restrict__ statesB, int hasB) {
    __shared__ float sred[8];
    int bid = blockIdx.x;
    int tid = threadIdx.x;
    int w = tid >> 6, lane = tid & 63;
    auto dotf = [&](const void* Wp, size_t roff, const float* x) -> float {
        float s = 0.f;
        if (BF) {
            const unsigned short* wrow = (const unsigned short*)Wp + roff;
            #pragma unroll
            for (int i = 0; i < 2; ++i) {
                int k = lane * 8 + i * 512;
                us8 wv = *(const us8*)(wrow + k);
                float4 x0 = *(const float4*)(x + k);
                float4 x1 = *(const float4*)(x + k + 4);
                s += bf2f(wv[0]) * x0.x + bf2f(wv[1]) * x0.y + bf2f(wv[2]) * x0.z + bf2f(wv[3]) * x0.w
                   + bf2f(wv[4]) * x1.x + bf2f(wv[5]) * x1.y + bf2f(wv[6]) * x1.z + bf2f(wv[7]) * x1.w;
            }
        } else {
            const float* wrow = (const float*)Wp + roff;
            #pragma unroll
            for (int i = 0; i < 4; ++i) {
                int k = lane * 4 + i * 256;
                float4 wv = *(const float4*)(wrow + k);
                float4 xv = *(const float4*)(x + k);
                s += wv.x * xv.x + wv.y * xv.y + wv.z * xv.z + wv.w * xv.w;
            }
        }
        return s;
    };
    if (bid < 512) {
        if (!hasA) return;
        int tt = w / 3, g = w - tt * 3;
        int jj = bid * 2 + tt;
        float s = dotf(WhhA, (size_t)(g * H + jj) * H, h0r);
        #pragma unroll
        for (int m = 1; m < 64; m <<= 1) s += __shfl_xor(s, m);
        if (lane == 0) sred[w] = s;
        __syncthreads();
        if (tid < 2) {
            int j2 = bid * 2 + tid;
            float s0 = sred[tid * 3], s1 = sred[tid * 3 + 1], s2 = sred[tid * 3 + 2];
            float r = sigmoidf_(giA[j2] + s0 + bhhA[j2]);
            float z = sigmoidf_(giA[H + j2] + s1 + bhhA[H + j2]);
            float n = tanhf(giA[2 * H + j2] + r * (s2 + bhhA[2 * H + j2]));
            float hn = (1.f - z) * n + z * h0r[j2];
            h0w[j2] = hn;
            if (statesA) statesA[j2] = hn;
        }
    } else {
        if (!hasB) return;
        int j = bid - 512;
        int hh = (w >= 3);
        int g = w - hh * 3;
        float s = dotf(hh ? WhhB : WihB, (size_t)(g * H + j) * H, hh ? h1r : h0r);
        #pragma unroll
        for (int m = 1; m < 64; m <<= 1) s += __shfl_xor(s, m);
        if (lane == 0) sred[w] = s;
        __syncthreads();
        if (tid == 0) {
            float r = sigmoidf_(sred[0] + bihB[j] + sred[3] + bhhB[j]);
            float z = sigmoidf_(sred[1] + bihB[H + j] + sred[4] + bhhB[H + j]);
            float n = tanhf(sred[2] + bihB[2 * H + j] + r * (sred[5] + bhhB[2 * H + j]));
            float hn = (1.f - z) * n + z * h1r[j];
            h1w[j] = hn;
            if (statesB) statesB[j] = hn;
        }
    }
}

// ---------------- scores GEMM, split-K (f32 weights) ----------------
#define SN 64
#define SK 64
__global__ __launch_bounds__(256) void scores_kernel(const float* __restrict__ states,
                                                     const float* __restrict__ W,
                                                     const float* __restrict__ bias,
                                                     float* __restrict__ dst, int kc_count) {
    __shared__ float As[SK][64 + 1];
    __shared__ float Bs[SK][SN + 1];
    int n0 = blockIdx.x * SN;
    int kc = blockIdx.y;
    int klen = H / kc_count;
    int kbeg = kc * klen;
    int tid = threadIdx.x;
    int tn = tid & 15, tm = tid >> 4;
    float acc[4][4] = {};
    for (int k0 = kbeg; k0 < kbeg + klen; k0 += SK) {
        for (int i = tid; i < 64 * (SK / 4); i += 256) {
            int m = i >> 4;
            int kq = i & 15;
            float4 v = *(const float4*)(states + (size_t)m * 2048 + H + k0 + kq * 4);
            As[kq * 4 + 0][m] = v.x; As[kq * 4 + 1][m] = v.y;
            As[kq * 4 + 2][m] = v.z; As[kq * 4 + 3][m] = v.w;
        }
        for (int i = tid; i < SN * (SK / 4); i += 256) {
            int n = i >> 4;
            int kq = i & 15;
            int r = n0 + n;
            float4 v = make_float4(0.f, 0.f, 0.f, 0.f);
            if (r < V) v = *(const float4*)(W + (size_t)r * H + k0 + kq * 4);
            Bs[kq * 4 + 0][n] = v.x; Bs[kq * 4 + 1][n] = v.y;
            Bs[kq * 4 + 2][n] = v.z; Bs[kq * 4 + 3][n] = v.w;
        }
        __syncthreads();
        #pragma unroll 8
        for (int k = 0; k < SK; ++k) {
            float a[4], b[4];
            #pragma unroll
            for (int i = 0; i < 4; ++i) a[i] = As[k][tm * 4 + i];
            #pragma unroll
            for (int j = 0; j < 4; ++j) b[j] = Bs[k][tn * 4 + j];
            #pragma unroll
            for (int i = 0; i < 4; ++i)
                #pragma unroll
                for (int j = 0; j < 4; ++j) acc[i][j] += a[i] * b[j];
        }
        __syncthreads();
    }
    if (kc_count == 1) {
        #pragma unroll
        for (int i = 0; i < 4; ++i) {
            int m = tm * 4 + i;
            #pragma unroll
            for (int j = 0; j < 4; ++j) {
                int r = n0 + tn * 4 + j;
                if (r < V) dst[(size_t)m * V + r] = acc[i][j] + bias[r];
            }
        }
    } else {
        #pragma unroll
        for (int i = 0; i < 4; ++i) {
            int m = tm * 4 + i;
            #pragma unroll
            for (int j = 0; j < 4; ++j) {
                int r = n0 + tn * 4 + j;
                dst[(size_t)(kc * 64 + m) * NPAD + r] = acc[i][j];
            }
        }
    }
}

__global__ __launch_bounds__(256) void reduce_scores_kernel(const float* __restrict__ part,
                                                            const float* __restrict__ bias,
                                                            float* __restrict__ out, int kc_count) {
    int e = blockIdx.x * 256 + threadIdx.x;
    if (e >= 64 * V) return;
    int m = e / V, r = e - m * V;
    float s = bias[r];
    for (int kc = 0; kc < kc_count; ++kc)
        s += part[(size_t)(kc * 64 + m) * NPAD + r];
    out[(size_t)m * V + r] = s;
}

extern "C" void kernel_launch(void* const* d_in, const int* in_sizes, int n_in,
                              void* d_out, int out_size, void* d_ws, size_t ws_size,
                              hipStream_t stream) {
    const int*   char_seq  = (const int*)d_in[0];
    const float* enc_state = (const float*)d_in[1];
    const int*   sos       = (const int*)d_in[2];
    const int*   tgt       = (const int*)d_in[5];
    const float* emb       = (const float*)d_in[6];
    const float* enc_Wih0  = (const float*)d_in[7];
    const float* enc_Whh0  = (const float*)d_in[8];
    const float* enc_bih0  = (const float*)d_in[9];
    const float* enc_bhh0  = (const float*)d_in[10];
    const float* enc_Wih1  = (const float*)d_in[11];
    const float* enc_Whh1  = (const float*)d_in[12];
    const float* enc_bih1  = (const float*)d_in[13];
    const float* enc_bhh1  = (const float*)d_in[14];
    const float* dec_Wih0  = (const float*)d_in[15];
    const float* dec_Whh0  = (const float*)d_in[16];
    const float* dec_bih0  = (const float*)d_in[17];
    const float* dec_bhh0  = (const float*)d_in[18];
    const float* dec_Wih1  = (const float*)d_in[19];
    const float* dec_Whh1  = (const float*)d_in[20];
    const float* dec_bih1  = (const float*)d_in[21];
    const float* dec_bhh1  = (const float*)d_in[22];
    const float* out_W     = (const float*)d_in[23];
    const float* out_b     = (const float*)d_in[24];

    float* ws = (float*)d_ws;
    float* e_enc   = ws;                       // 64*512
    float* e_dec   = e_enc + SEQ * EMB;        // 64*512
    float* gi_enc0 = e_dec + SEQ * EMB;        // 64*3072
    float* gi_dec0 = gi_enc0 + SEQ * H3;       // 64*3072
    ull*   h0hist  = (ull*)(gi_dec0 + SEQ * H3);        // NPH*1024 ull
    ull*   h1hist  = h0hist + (size_t)NPH * 1024;       // NPH*1024 ull
    float* h0buf   = (float*)(h1hist + (size_t)NPH * 1024);  // 2*1024 (fallback)
    float* h1buf   = h0buf + 2 * H;                          // 2*1024 (fallback)
    float* cur     = h1buf + 2 * H;
    size_t base = (size_t)(cur - ws);
    size_t avail = ws_size / 4 > base ? ws_size / 4 - base : 0;

    const size_t REC_ELEMS = (size_t)H3 * H;   // per matrix
    const size_t REC_SLOTS = REC_ELEMS / 2;    // float-slots per bf16 matrix

    int bf_rec = (avail >= 6 * REC_SLOTS);
    unsigned short* wbf0 = nullptr;
    if (bf_rec) { wbf0 = (unsigned short*)cur; cur += 6 * REC_SLOTS; avail -= 6 * REC_SLOTS; }
    int KC = 1;
    if (avail >= (size_t)8 * 64 * NPAD) KC = 8;
    else if (avail >= (size_t)4 * 64 * NPAD) KC = 4;
    else if (avail >= (size_t)2 * 64 * NPAD) KC = 2;
    float* partials = cur;

    float* scores = (float*)d_out;             // 64*10000
    float* states = scores + SEQ * V;          // 64*2048

    // ---- merged prep: conversion + history init + embedding ----
    PrepArgs pg;
    pg.src[0] = enc_Whh0; pg.src[1] = enc_Wih1; pg.src[2] = enc_Whh1;
    pg.src[3] = dec_Whh0; pg.src[4] = dec_Wih1; pg.src[5] = dec_Whh1;
    pg.dst0 = wbf0; pg.doConv = bf_rec;
    pg.enc_state = enc_state; pg.h0hist = h0hist; pg.h1hist = h1hist;
    pg.h0buf = h0buf; pg.h1buf = h1buf;
    pg.cs = char_seq; pg.sos = sos; pg.tgt = tgt; pg.emb = emb;
    pg.e_enc = e_enc; pg.e_dec = e_dec;
    prep_kernel<<<9860, 256, 0, stream>>>(pg);
    gi_gemm_kernel<<<dim3(H3 / 64, 2), 256, 0, stream>>>(e_enc, enc_Wih0, enc_bih0, gi_enc0,
                                                         e_dec, dec_Wih0, dec_bih0, gi_dec0);

    bool done = false;
    if (bf_rec) {
        PArgs pa;
        pa.encWhh0 = wbf0;
        pa.encWih1 = wbf0 + REC_ELEMS;
        pa.encWhh1 = wbf0 + 2 * REC_ELEMS;
        pa.decWhh0 = wbf0 + 3 * REC_ELEMS;
        pa.decWih1 = wbf0 + 4 * REC_ELEMS;
        pa.decWhh1 = wbf0 + 5 * REC_ELEMS;
        pa.gi_enc0 = gi_enc0; pa.gi_dec0 = gi_dec0;
        pa.enc_bhh0 = enc_bhh0; pa.dec_bhh0 = dec_bhh0;
        pa.enc_bih1 = enc_bih1; pa.enc_bhh1 = enc_bhh1;
        pa.dec_bih1 = dec_bih1; pa.dec_bhh1 = dec_bhh1;
        pa.h0hist = h0hist; pa.h1hist = h1hist; pa.states = states;
        void* kparams[] = { (void*)&pa };
        hipError_t err = hipLaunchCooperativeKernel((const void*)persist_kernel,
                                                    dim3(192), dim3(1024), kparams, 0, stream);
        done = (err == hipSuccess);
    }

    if (!done) {
        for (int p = 0; p <= 128; ++p) {
            int hasA = (p <= 127);
            int hasB = (p >= 1);
            const float* giA = nullptr; const void* WhhA = nullptr; const float* bhhA = nullptr;
            float* statesA = nullptr;
            if (hasA) {
                if (p < 64) {
                    giA = gi_enc0 + (size_t)p * H3; bhhA = enc_bhh0;
                    WhhA = bf_rec ? (const void*)wbf0 : (const void*)enc_Whh0;
                } else {
                    int t = p - 64;
                    giA = gi_dec0 + (size_t)t * H3; bhhA = dec_bhh0;
                    WhhA = bf_rec ? (const void*)(wbf0 + 3 * REC_ELEMS) : (const void*)dec_Whh0;
                    statesA = states + (size_t)t * 2048;
                }
            }
            const void *WihB = nullptr, *WhhB = nullptr;
            const float *bihB = nullptr, *bhhB = nullptr;
            float* statesB = nullptr;
            if (hasB) {
                if (p <= 64) {
                    bihB = enc_bih1; bhhB = enc_bhh1;
                    WihB = bf_rec ? (const void*)(wbf0 + REC_ELEMS) : (const void*)enc_Wih1;
                    WhhB = bf_rec ? (const void*)(wbf0 + 2 * REC_ELEMS) : (const void*)enc_Whh1;
                } else {
                    int t = p - 65;
                    bihB = dec_bih1; bhhB = dec_bhh1;
                    WihB = bf_rec ? (const void*)(wbf0 + 4 * REC_ELEMS) : (const void*)dec_Wih1;
                    WhhB = bf_rec ? (const void*)(wbf0 + 5 * REC_ELEMS) : (const void*)dec_Whh1;
                    statesB = states + (size_t)t * 2048 + H;
                }
            }
            float* h0r = h0buf + (p & 1) * H;
            float* h0w = h0buf + ((p + 1) & 1) * H;
            float* h1r = h1buf + (p & 1) * H;
            float* h1w = h1buf + ((p + 1) & 1) * H;
            if (bf_rec)
                phase_kernel<1><<<1536, 384, 0, stream>>>(giA, WhhA, bhhA, h0r, h0w, statesA, hasA,
                                                          WihB, bihB, WhhB, bhhB, h1r, h1w, statesB, hasB);
            else
                phase_kernel<0><<<1536, 384, 0, stream>>>(giA, WhhA, bhhA, h0r, h0w, statesA, hasA,
                                                          WihB, bihB, WhhB, bhhB, h1r, h1w, statesB, hasB);
        }
    }

    if (KC == 1) {
        scores_kernel<<<dim3((V + SN - 1) / SN, 1), 256, 0, stream>>>(states, out_W, out_b, scores, 1);
    } else {
        scores_kernel<<<dim3((V + SN - 1) / SN, KC), 256, 0, stream>>>(states, out_W, out_b, partials, KC);
        reduce_scores_kernel<<<(64 * V + 255) / 256, 256, 0, stream>>>(partials, out_b, scores, KC);
    }
}